// Round 3
// baseline (165.898 us; speedup 1.0000x reference)
//
#include <hip/hip_runtime.h>
#include <hip/hip_bf16.h>

#define Bn 32
#define Tn 16384
#define Ln 16
#define Sn 128
#define Hn 512
#define Cn 10
#define Kn 48
#define TOUT 16369
#define CH 512
#define NCH 32
#define XLEN 560            // ushort pitch per (phase,channel) row; 1120 B (16B-aligned)
#define SPITCH 52           // float pitch for staged shapelets (breaks 16-way conflict)

typedef short  s16x8  __attribute__((ext_vector_type(8)));
typedef float  f32x16 __attribute__((ext_vector_type(16)));

__device__ __forceinline__ unsigned short f2bf(float f) {
    union { float f; unsigned int u; } v; v.f = f;
    unsigned int r = v.u + 0x7FFF + ((v.u >> 16) & 1);   // RNE
    return (unsigned short)(r >> 16);
}

// ---------------------------------------------------------------- distance
__global__ __launch_bounds__(256, 3) void dist_kernel(const float* __restrict__ x,
                                                      const float* __restrict__ sh,
                                                      float* __restrict__ partial) {
    __shared__ unsigned short xph[24 * XLEN];   // 26880 B; aliased fp32 shapelet stage first
    __shared__ float winsq_lds[CH];             // 2048 B
    __shared__ float wavemin[4 * Sn];           // 2048 B

    const int tid   = threadIdx.x;
    const int b     = blockIdx.x >> 5;
    const int chunk = blockIdx.x & 31;
    const int tb    = chunk * CH;
    const int lane  = tid & 63;
    const int w     = tid >> 6;
    const int n     = lane & 31;     // MFMA row (A) / col (B,C)
    const int h     = lane >> 5;     // k-half select

    // ---- 1) stage shapelets fp32 -> LDS, pitch 52 (128*52*4 = 26624 B <= 26880)
    float* shf = (float*)xph;
    {
        const float4* s4 = (const float4*)sh;
        for (int i = tid; i < Sn * (Kn / 4); i += 256) {
            const int s = i / 12, q = i - s * 12;
            ((float4*)(shf + s * SPITCH))[q] = s4[i];
        }
    }
    __syncthreads();

    // ---- 2) B-fragments (shapelets * -2, bf16) + shsq (fp32 exact)
    s16x8 bfr[3][4];
    float shsqv[4];
    #pragma unroll
    for (int st = 0; st < 4; ++st) {
        const int s = st * 32 + n;
        const float* row = shf + s * SPITCH;
        float q = 0.f;
        #pragma unroll
        for (int k = 0; k < Kn; ++k) q = fmaf(row[k], row[k], q);
        shsqv[st] = q;
        #pragma unroll
        for (int kk = 0; kk < 3; ++kk)
            #pragma unroll
            for (int j = 0; j < 8; ++j)
                bfr[kk][st][j] = (short)f2bf(-2.0f * row[kk * 16 + 8 * h + j]);
    }
    __syncthreads();   // done reading shf; xph region reusable

    // ---- 3a) phase 0: convert x -> bf16 once (guarded)
    const float* xb = x + b * 3 * Tn;
    unsigned int* xpu = (unsigned int*)xph;     // u32 view; row pitch XLEN/2 = 280
    for (int idx = tid; idx < 3 * 272; idx += 256) {
        const int d = idx / 272, e = idx - d * 272;
        const int t0 = tb + 2 * e;
        const float f0 = (t0     < Tn) ? xb[d * Tn + t0]     : 0.f;
        const float f1 = (t0 + 1 < Tn) ? xb[d * Tn + t0 + 1] : 0.f;
        xpu[d * (XLEN / 2) + e] = (unsigned int)f2bf(f0) | ((unsigned int)f2bf(f1) << 16);
    }

    // ---- 3b) winsq fp32 (exact; sliding window from global, L1-warm)
    {
        const int i0 = tid * 2;
        const int t0 = tb + i0;
        float q0 = 0.f, q1 = 0.f;
        #pragma unroll
        for (int d = 0; d < 3; ++d) {
            const float* xd = xb + d * Tn + t0;
            float wv[17];
            #pragma unroll
            for (int l = 0; l < 17; ++l) wv[l] = (t0 + l < Tn) ? xd[l] : 0.f;
            float s = 0.f;
            #pragma unroll
            for (int l = 0; l < 16; ++l) s = fmaf(wv[l], wv[l], s);
            q0 += s;
            s = s - wv[0] * wv[0] + wv[16] * wv[16];
            q1 += s;
        }
        winsq_lds[i0    ] = (t0     >= TOUT) ? 1e30f : q0;
        winsq_lds[i0 + 1] = (t0 + 1 >= TOUT) ? 1e30f : q1;
    }
    __syncthreads();

    // ---- 3c) phases 1..7 from phase 0 via u32 copies / funnel shifts
    for (int p = 1; p < 8; ++p) {
        const int half = p >> 1;
        for (int idx = tid; idx < 3 * 268; idx += 256) {
            const int d = idx / 268, e = idx - d * 268;
            const unsigned int* src = xpu + d * (XLEN / 2);
            unsigned int val;
            if (p & 1) {
                const unsigned int A = src[e + half];
                const unsigned int B = src[e + half + 1];
                val = (A >> 16) | (B << 16);
            } else {
                val = src[e + half];
            }
            xpu[(p * 3 + d) * (XLEN / 2) + e] = val;
        }
    }
    __syncthreads();

    // ---- 4) main MFMA loop: 4 tiles per wave, 2 shapelet-groups per pass
    const f32x16 zero16 = {0.f, 0.f, 0.f, 0.f, 0.f, 0.f, 0.f, 0.f,
                           0.f, 0.f, 0.f, 0.f, 0.f, 0.f, 0.f, 0.f};
    float mcol[4] = {1e30f, 1e30f, 1e30f, 1e30f};

    for (int rr = 0; rr < 4; ++rr) {
        const int i  = 4 * w + rr;              // tile base offset in chunk [0,16)
        const int p  = i & 7;
        const int ib = i & ~7;
        const int u0 = ib + 16 * n + 8 * h;     // 16B-aligned element offset
        const unsigned short* xp = &xph[p * 3 * XLEN + u0];
        const s16x8 a0 = *(const s16x8*)(const void*)(xp);
        const s16x8 a1 = *(const s16x8*)(const void*)(xp + XLEN);
        const s16x8 a2 = *(const s16x8*)(const void*)(xp + 2 * XLEN);

        #pragma unroll
        for (int sp = 0; sp < 2; ++sp) {        // two passes: live acc = 32 regs
            f32x16 acc[2];
            #pragma unroll
            for (int q = 0; q < 2; ++q) {
                const int st = sp * 2 + q;
                acc[q] = __builtin_amdgcn_mfma_f32_32x32x16_bf16(a0, bfr[0][st], zero16, 0, 0, 0);
                acc[q] = __builtin_amdgcn_mfma_f32_32x32x16_bf16(a1, bfr[1][st], acc[q], 0, 0, 0);
                acc[q] = __builtin_amdgcn_mfma_f32_32x32x16_bf16(a2, bfr[2][st], acc[q], 0, 0, 0);
            }
            #pragma unroll
            for (int reg = 0; reg < 16; reg += 2) {
                const int row0 = (reg & 3) + 8 * (reg >> 2) + 4 * h;
                const float w0 = winsq_lds[i + 16 * row0];
                const float w1 = winsq_lds[i + 16 * (row0 + 1)];
                #pragma unroll
                for (int q = 0; q < 2; ++q) {
                    const int st = sp * 2 + q;
                    const float u = acc[q][reg]     + w0;
                    const float v = acc[q][reg + 1] + w1;
                    mcol[st] = fminf(fminf(mcol[st], u), v);   // v_min3
                }
            }
        }
    }

    // ---- 5) reduce: +shsq once, lanes n / n+32 share column s = st*32+n
    #pragma unroll
    for (int st = 0; st < 4; ++st) {
        float mm = mcol[st] + shsqv[st];
        mm = fminf(mm, __shfl_xor(mm, 32, 64));
        if (h == 0) wavemin[w * Sn + st * 32 + n] = mm;
    }
    __syncthreads();
    if (tid < Sn) {
        const float mm = fminf(fminf(wavemin[tid], wavemin[Sn + tid]),
                               fminf(wavemin[2 * Sn + tid], wavemin[3 * Sn + tid]));
        partial[(b * NCH + chunk) * Sn + tid] = mm;
    }
}

// ------------------------------------------- final min over chunks + MLP head
__global__ __launch_bounds__(512) void mlp_kernel(const float* __restrict__ partial,
                                                  const float* __restrict__ W1,
                                                  const float* __restrict__ b1,
                                                  const float* __restrict__ W2,
                                                  const float* __restrict__ b2,
                                                  float* __restrict__ out) {
    __shared__ float pmin[4][Sn];
    __shared__ float db[Sn];
    __shared__ float hb[Hn];
    __shared__ float part[Cn][32];
    const int b = blockIdx.x, tid = threadIdx.x;

    // cooperative min over 32 chunks: 512 threads = 4 groups x 128 s
    {
        const int s = tid & 127, g = tid >> 7;
        const float* pp = partial + (b * NCH + g * 8) * Sn + s;
        float m = pp[0];
        #pragma unroll
        for (int c = 1; c < 8; ++c) m = fminf(m, pp[c * Sn]);
        pmin[g][s] = m;
    }
    __syncthreads();
    if (tid < Sn) {
        const float m = fminf(fminf(pmin[0][tid], pmin[1][tid]),
                              fminf(pmin[2][tid], pmin[3][tid]));
        db[tid] = m;
        out[b * Sn + tid] = m;             // distance output
    }
    __syncthreads();

    float a = b1[tid];
    const float4* w1r = (const float4*)(W1 + tid * Sn);
    const float4* dbv = (const float4*)db;
    #pragma unroll
    for (int i = 0; i < Sn / 4; ++i) {
        const float4 wv = w1r[i];
        const float4 dv = dbv[i];
        a = fmaf(dv.x, wv.x, a); a = fmaf(dv.y, wv.y, a);
        a = fmaf(dv.z, wv.z, a); a = fmaf(dv.w, wv.w, a);
    }
    hb[tid] = fmaxf(a, 0.0f);
    __syncthreads();

    if (tid < Cn * 32) {
        const int c = tid >> 5, p = tid & 31;
        float acc = 0.f;
        #pragma unroll
        for (int i = 0; i < Hn / 32; ++i)
            acc = fmaf(hb[p + 32 * i], W2[c * Hn + p + 32 * i], acc);
        part[c][p] = acc;
    }
    __syncthreads();
    if (tid < Cn) {
        float acc = b2[tid];
        #pragma unroll
        for (int p = 0; p < 32; ++p) acc += part[tid][p];
        out[Bn * Sn + b * Cn + tid] = acc; // classification output
    }
}

// ----------------------------------------------------------------- launcher
extern "C" void kernel_launch(void* const* d_in, const int* in_sizes, int n_in,
                              void* d_out, int out_size, void* d_ws, size_t ws_size,
                              hipStream_t stream) {
    const float* x  = (const float*)d_in[0];
    const float* sh = (const float*)d_in[1];
    const float* W1 = (const float*)d_in[2];
    const float* b1 = (const float*)d_in[3];
    const float* W2 = (const float*)d_in[4];
    const float* b2 = (const float*)d_in[5];
    float* out = (float*)d_out;
    float* partial = (float*)d_ws;   // 32*32*128 floats = 512 KB

    dist_kernel<<<Bn * NCH, 256, 0, stream>>>(x, sh, partial);
    mlp_kernel<<<Bn, 512, 0, stream>>>(partial, W1, b1, W2, b2, out);
}

// Round 4
// 119.992 us; speedup vs baseline: 1.3826x; 1.3826x over previous
//
#include <hip/hip_runtime.h>
#include <hip/hip_bf16.h>

#define Bn 32
#define Tn 16384
#define Ln 16
#define Sn 128
#define Hn 512
#define Cn 10
#define Kn 48
#define TOUT 16369
#define CH 512
#define NCH 32
#define XLEN 560            // ushort pitch per (phase,channel) row; 1120 B (16B-aligned)
#define SPITCH 52           // float pitch for staged shapelets (breaks 16-way conflict)

typedef short  s16x8  __attribute__((ext_vector_type(8)));
typedef float  f32x16 __attribute__((ext_vector_type(16)));

__device__ __forceinline__ unsigned short f2bf(float f) {
    union { float f; unsigned int u; } v; v.f = f;
    unsigned int r = v.u + 0x7FFF + ((v.u >> 16) & 1);   // RNE
    return (unsigned short)(r >> 16);
}

// ---------------------------------------------------------------- distance
// (256,2): 2 waves/SIMD budget = 256 VGPR/wave. (256,3) spilled ~1KB/thread
// to scratch -> 300 MB HBM traffic, 94us. Do NOT raise the occupancy bound.
__global__ __launch_bounds__(256, 2) void dist_kernel(const float* __restrict__ x,
                                                      const float* __restrict__ sh,
                                                      float* __restrict__ partial) {
    __shared__ unsigned short xph[24 * XLEN];   // 26880 B; aliased fp32 shapelet stage first
    __shared__ float winsq_lds[CH];             // 2048 B
    __shared__ float wavemin[4 * Sn];           // 2048 B

    const int tid   = threadIdx.x;
    const int b     = blockIdx.x >> 5;
    const int chunk = blockIdx.x & 31;
    const int tb    = chunk * CH;
    const int lane  = tid & 63;
    const int w     = tid >> 6;
    const int n     = lane & 31;     // MFMA row (A) / col (B,C)
    const int h     = lane >> 5;     // k-half select

    // ---- 1) stage shapelets fp32 -> LDS, pitch 52 (128*52*4 = 26624 B <= 26880)
    float* shf = (float*)xph;
    {
        const float4* s4 = (const float4*)sh;
        for (int i = tid; i < Sn * (Kn / 4); i += 256) {
            const int s = i / 12, q = i - s * 12;
            ((float4*)(shf + s * SPITCH))[q] = s4[i];
        }
    }
    __syncthreads();

    // ---- 2) B-fragments (shapelets * -2, bf16) + shsq (fp32 exact)
    s16x8 bfr[3][4];
    float shsqv[4];
    #pragma unroll
    for (int st = 0; st < 4; ++st) {
        const int s = st * 32 + n;
        const float* row = shf + s * SPITCH;
        float q = 0.f;
        #pragma unroll
        for (int k = 0; k < Kn; ++k) q = fmaf(row[k], row[k], q);
        shsqv[st] = q;
        #pragma unroll
        for (int kk = 0; kk < 3; ++kk)
            #pragma unroll
            for (int j = 0; j < 8; ++j)
                bfr[kk][st][j] = (short)f2bf(-2.0f * row[kk * 16 + 8 * h + j]);
    }
    __syncthreads();   // done reading shf; xph region reusable

    // ---- 3a) phase 0: convert x -> bf16 once (guarded)
    const float* xb = x + b * 3 * Tn;
    unsigned int* xpu = (unsigned int*)xph;     // u32 view; row pitch XLEN/2 = 280
    for (int idx = tid; idx < 3 * 272; idx += 256) {
        const int d = idx / 272, e = idx - d * 272;
        const int t0 = tb + 2 * e;
        const float f0 = (t0     < Tn) ? xb[d * Tn + t0]     : 0.f;
        const float f1 = (t0 + 1 < Tn) ? xb[d * Tn + t0 + 1] : 0.f;
        xpu[d * (XLEN / 2) + e] = (unsigned int)f2bf(f0) | ((unsigned int)f2bf(f1) << 16);
    }

    // ---- 3b) winsq fp32 (exact; sliding window from global, L1-warm)
    {
        const int i0 = tid * 2;
        const int t0 = tb + i0;
        float q0 = 0.f, q1 = 0.f;
        #pragma unroll
        for (int d = 0; d < 3; ++d) {
            const float* xd = xb + d * Tn + t0;
            float wv[17];
            #pragma unroll
            for (int l = 0; l < 17; ++l) wv[l] = (t0 + l < Tn) ? xd[l] : 0.f;
            float s = 0.f;
            #pragma unroll
            for (int l = 0; l < 16; ++l) s = fmaf(wv[l], wv[l], s);
            q0 += s;
            s = s - wv[0] * wv[0] + wv[16] * wv[16];
            q1 += s;
        }
        winsq_lds[i0    ] = (t0     >= TOUT) ? 1e30f : q0;
        winsq_lds[i0 + 1] = (t0 + 1 >= TOUT) ? 1e30f : q1;
    }
    __syncthreads();

    // ---- 3c) phases 1..7 from phase 0 via u32 copies / funnel shifts
    for (int p = 1; p < 8; ++p) {
        const int half = p >> 1;
        for (int idx = tid; idx < 3 * 268; idx += 256) {
            const int d = idx / 268, e = idx - d * 268;
            const unsigned int* src = xpu + d * (XLEN / 2);
            unsigned int val;
            if (p & 1) {
                const unsigned int A = src[e + half];
                const unsigned int B = src[e + half + 1];
                val = (A >> 16) | (B << 16);
            } else {
                val = src[e + half];
            }
            xpu[(p * 3 + d) * (XLEN / 2) + e] = val;
        }
    }
    __syncthreads();

    // ---- 4) main MFMA loop: 4 tiles per wave, single 4-accumulator pass
    const f32x16 zero16 = {0.f, 0.f, 0.f, 0.f, 0.f, 0.f, 0.f, 0.f,
                           0.f, 0.f, 0.f, 0.f, 0.f, 0.f, 0.f, 0.f};
    float mcol[4] = {1e30f, 1e30f, 1e30f, 1e30f};

    for (int rr = 0; rr < 4; ++rr) {
        const int i  = 4 * w + rr;              // tile base offset in chunk [0,16)
        const int p  = i & 7;
        const int ib = i & ~7;
        const int u0 = ib + 16 * n + 8 * h;     // 16B-aligned element offset
        const unsigned short* xp = &xph[p * 3 * XLEN + u0];
        const s16x8 a0 = *(const s16x8*)(const void*)(xp);
        const s16x8 a1 = *(const s16x8*)(const void*)(xp + XLEN);
        const s16x8 a2 = *(const s16x8*)(const void*)(xp + 2 * XLEN);

        f32x16 acc[4];
        #pragma unroll
        for (int st = 0; st < 4; ++st) {
            acc[st] = __builtin_amdgcn_mfma_f32_32x32x16_bf16(a0, bfr[0][st], zero16, 0, 0, 0);
            acc[st] = __builtin_amdgcn_mfma_f32_32x32x16_bf16(a1, bfr[1][st], acc[st], 0, 0, 0);
            acc[st] = __builtin_amdgcn_mfma_f32_32x32x16_bf16(a2, bfr[2][st], acc[st], 0, 0, 0);
        }

        #pragma unroll
        for (int reg = 0; reg < 16; reg += 2) {
            const int row0 = (reg & 3) + 8 * (reg >> 2) + 4 * h;
            const float w0 = winsq_lds[i + 16 * row0];
            const float w1 = winsq_lds[i + 16 * (row0 + 1)];
            #pragma unroll
            for (int st = 0; st < 4; ++st) {
                const float u = acc[st][reg]     + w0;
                const float v = acc[st][reg + 1] + w1;
                mcol[st] = fminf(fminf(mcol[st], u), v);   // v_min3
            }
        }
    }

    // ---- 5) reduce: +shsq once, lanes n / n+32 share column s = st*32+n
    #pragma unroll
    for (int st = 0; st < 4; ++st) {
        float mm = mcol[st] + shsqv[st];
        mm = fminf(mm, __shfl_xor(mm, 32, 64));
        if (h == 0) wavemin[w * Sn + st * 32 + n] = mm;
    }
    __syncthreads();
    if (tid < Sn) {
        const float mm = fminf(fminf(wavemin[tid], wavemin[Sn + tid]),
                               fminf(wavemin[2 * Sn + tid], wavemin[3 * Sn + tid]));
        partial[(b * NCH + chunk) * Sn + tid] = mm;
    }
}

// ------------------------------------------- final min over chunks + MLP head
__global__ __launch_bounds__(512) void mlp_kernel(const float* __restrict__ partial,
                                                  const float* __restrict__ W1,
                                                  const float* __restrict__ b1,
                                                  const float* __restrict__ W2,
                                                  const float* __restrict__ b2,
                                                  float* __restrict__ out) {
    __shared__ float pmin[4][Sn];
    __shared__ float db[Sn];
    __shared__ float hb[Hn];
    __shared__ float part[Cn][32];
    const int b = blockIdx.x, tid = threadIdx.x;

    // cooperative min over 32 chunks: 512 threads = 4 groups x 128 s
    {
        const int s = tid & 127, g = tid >> 7;
        const float* pp = partial + (b * NCH + g * 8) * Sn + s;
        float m = pp[0];
        #pragma unroll
        for (int c = 1; c < 8; ++c) m = fminf(m, pp[c * Sn]);
        pmin[g][s] = m;
    }
    __syncthreads();
    if (tid < Sn) {
        const float m = fminf(fminf(pmin[0][tid], pmin[1][tid]),
                              fminf(pmin[2][tid], pmin[3][tid]));
        db[tid] = m;
        out[b * Sn + tid] = m;             // distance output
    }
    __syncthreads();

    float a = b1[tid];
    const float4* w1r = (const float4*)(W1 + tid * Sn);
    const float4* dbv = (const float4*)db;
    #pragma unroll
    for (int i = 0; i < Sn / 4; ++i) {
        const float4 wv = w1r[i];
        const float4 dv = dbv[i];
        a = fmaf(dv.x, wv.x, a); a = fmaf(dv.y, wv.y, a);
        a = fmaf(dv.z, wv.z, a); a = fmaf(dv.w, wv.w, a);
    }
    hb[tid] = fmaxf(a, 0.0f);
    __syncthreads();

    if (tid < Cn * 32) {
        const int c = tid >> 5, p = tid & 31;
        float acc = 0.f;
        #pragma unroll
        for (int i = 0; i < Hn / 32; ++i)
            acc = fmaf(hb[p + 32 * i], W2[c * Hn + p + 32 * i], acc);
        part[c][p] = acc;
    }
    __syncthreads();
    if (tid < Cn) {
        float acc = b2[tid];
        #pragma unroll
        for (int p = 0; p < 32; ++p) acc += part[tid][p];
        out[Bn * Sn + b * Cn + tid] = acc; // classification output
    }
}

// ----------------------------------------------------------------- launcher
extern "C" void kernel_launch(void* const* d_in, const int* in_sizes, int n_in,
                              void* d_out, int out_size, void* d_ws, size_t ws_size,
                              hipStream_t stream) {
    const float* x  = (const float*)d_in[0];
    const float* sh = (const float*)d_in[1];
    const float* W1 = (const float*)d_in[2];
    const float* b1 = (const float*)d_in[3];
    const float* W2 = (const float*)d_in[4];
    const float* b2 = (const float*)d_in[5];
    float* out = (float*)d_out;
    float* partial = (float*)d_ws;   // 32*32*128 floats = 512 KB

    dist_kernel<<<Bn * NCH, 256, 0, stream>>>(x, sh, partial);
    mlp_kernel<<<Bn, 512, 0, stream>>>(partial, W1, b1, W2, b2, out);
}

// Round 5
// 114.710 us; speedup vs baseline: 1.4462x; 1.0460x over previous
//
#include <hip/hip_runtime.h>
#include <hip/hip_bf16.h>

#define Bn 32
#define Tn 16384
#define Ln 16
#define Sn 128
#define Hn 512
#define Cn 10
#define Kn 48
#define TOUT 16369
#define CH 1024
#define NCH 16
#define XLEN 1056            // bf16 elems per (phase,channel) row (66 spans of 16)
#define XDW  (XLEN / 2)      // 528 dwords per row
#define XGRP (XLEN / 8)      // 132 16-B groups per row

typedef short  s16x8  __attribute__((ext_vector_type(8)));
typedef float  f32x16 __attribute__((ext_vector_type(16)));

__device__ __forceinline__ unsigned short f2bf(float f) {
    union { float f; unsigned int u; } v; v.f = f;
    unsigned int r = v.u + 0x7FFF + ((v.u >> 16) & 1);   // RNE
    return (unsigned short)(r >> 16);
}

// XOR bank swizzle on 16-B groups: permutes within each aligned 128-B block,
// so it is size-preserving. Makes the main-loop ds_read_b128 pattern
// (lane n -> group base+2n+h) fully conflict-free.
__device__ __forceinline__ int swz(int g) { return g ^ ((g >> 3) & 7); }

// ---------------------------------------------------------------- distance
// (256,2): 256-reg/wave budget. (256,3) spilled (R3: 300MB, 94us). The R4
// spill (74MB writes) came from high-pressure LDS staging sections; this
// version uses global-direct bfr + register-funnel staging to keep every
// section's live set small.
__global__ __launch_bounds__(256, 2) void dist_kernel(const float* __restrict__ x,
                                                      const float* __restrict__ sh,
                                                      float* __restrict__ partial) {
    __shared__ unsigned int xph[24 * XDW];      // 50688 B  (8 phases x 3 ch)
    __shared__ float wsq[16 * 64];              //  4096 B  (winsq, [i_low][m64])
    __shared__ float wavemin[4 * Sn];           //  2048 B

    const int tid   = threadIdx.x;
    const int b     = blockIdx.x >> 4;
    const int chunk = blockIdx.x & 15;
    const int tb    = chunk * CH;
    const int lane  = tid & 63;
    const int w     = tid >> 6;
    const int n     = lane & 31;     // MFMA row (A) / col (B,C)
    const int h     = lane >> 5;     // k-half select
    const bool interior = (tb + XLEN + 8) <= Tn;   // chunks 0..14

    // ---- 1) B-fragments (-2*shapelet, bf16) + shsq (exact fp32), direct from
    //         global (24 KB, L1/L2-hot). No LDS, no sync, tiny live set.
    s16x8 bfr[3][4];
    float shsqv[4];
    #pragma unroll
    for (int st = 0; st < 4; ++st) {
        const float4* row4 = (const float4*)(sh + (st * 32 + n) * Kn);
        float q = 0.f;
        #pragma unroll
        for (int c = 0; c < 12; ++c) {
            const float4 v = row4[c];
            q = fmaf(v.x, v.x, q); q = fmaf(v.y, v.y, q);
            q = fmaf(v.z, v.z, q); q = fmaf(v.w, v.w, q);
        }
        shsqv[st] = q;
        #pragma unroll
        for (int kk = 0; kk < 3; ++kk) {
            const float4 va = row4[kk * 4 + 2 * h];
            const float4 vb = row4[kk * 4 + 2 * h + 1];
            bfr[kk][st][0] = (short)f2bf(-2.0f * va.x);
            bfr[kk][st][1] = (short)f2bf(-2.0f * va.y);
            bfr[kk][st][2] = (short)f2bf(-2.0f * va.z);
            bfr[kk][st][3] = (short)f2bf(-2.0f * va.w);
            bfr[kk][st][4] = (short)f2bf(-2.0f * vb.x);
            bfr[kk][st][5] = (short)f2bf(-2.0f * vb.y);
            bfr[kk][st][6] = (short)f2bf(-2.0f * vb.z);
            bfr[kk][st][7] = (short)f2bf(-2.0f * vb.w);
        }
    }

    // ---- 2) stage x as 8 phase-shifted bf16 copies, register-funnel method:
    //         load span once, convert once, produce phases with shifts.
    if (tid < 198) {
        const int ch = tid / 66, j = tid - ch * 66;     // span j: elems [16j,16j+16)
        const float* xs = x + (b * 3 + ch) * Tn + tb + 16 * j;
        float in[24];
        if (interior) {
            const float4* x4 = (const float4*)xs;
            #pragma unroll
            for (int q = 0; q < 6; ++q) {
                const float4 v = x4[q];
                in[4 * q] = v.x; in[4 * q + 1] = v.y; in[4 * q + 2] = v.z; in[4 * q + 3] = v.w;
            }
        } else {
            #pragma unroll
            for (int k = 0; k < 24; ++k) {
                const int t = tb + 16 * j + k;
                in[k] = (t < Tn) ? xs[k] : 0.f;
            }
        }
        unsigned int r[12];
        #pragma unroll
        for (int q = 0; q < 12; ++q)
            r[q] = (unsigned int)f2bf(in[2 * q]) | ((unsigned int)f2bf(in[2 * q + 1]) << 16);

        #pragma unroll
        for (int p = 0; p < 8; ++p) {
            unsigned int v[8];
            #pragma unroll
            for (int e = 0; e < 8; ++e) {
                const int o = 2 * e + p;
                v[e] = (o & 1) ? ((r[o >> 1] >> 16) | (r[(o >> 1) + 1] << 16))
                               : r[o >> 1];
            }
            const int gb = (p * 3 + ch) * XGRP + 2 * j;
            uint4 lo = {v[0], v[1], v[2], v[3]};
            uint4 hi4 = {v[4], v[5], v[6], v[7]};
            *(uint4*)((char*)xph + (swz(gb)     << 4)) = lo;
            *(uint4*)((char*)xph + (swz(gb + 1) << 4)) = hi4;
        }
    }

    // ---- 3) winsq (exact fp32), stored transposed: wsq[(t&15)*64 + (t>>4)]
    {
        const int t0 = 4 * tid;                        // local t, 4 per thread
        float q0 = 0.f, q1 = 0.f, q2 = 0.f, q3 = 0.f;
        #pragma unroll
        for (int ch = 0; ch < 3; ++ch) {
            const float* xd = x + (b * 3 + ch) * Tn + tb + t0;
            float wv[19];
            if (interior) {
                const float4* x4 = (const float4*)xd;
                #pragma unroll
                for (int q = 0; q < 4; ++q) {
                    const float4 v = x4[q];
                    wv[4 * q] = v.x; wv[4 * q + 1] = v.y; wv[4 * q + 2] = v.z; wv[4 * q + 3] = v.w;
                }
                wv[16] = xd[16]; wv[17] = xd[17]; wv[18] = xd[18];
            } else {
                #pragma unroll
                for (int l = 0; l < 19; ++l)
                    wv[l] = (tb + t0 + l < Tn) ? xd[l] : 0.f;
            }
            float s = 0.f;
            #pragma unroll
            for (int l = 0; l < 16; ++l) s = fmaf(wv[l], wv[l], s);
            q0 += s;
            s = s - wv[0] * wv[0] + wv[16] * wv[16]; q1 += s;
            s = s - wv[1] * wv[1] + wv[17] * wv[17]; q2 += s;
            s = s - wv[2] * wv[2] + wv[18] * wv[18]; q3 += s;
        }
        const float qs[4] = {q0, q1, q2, q3};
        #pragma unroll
        for (int c = 0; c < 4; ++c) {
            const int t = t0 + c;
            wsq[(t & 15) * 64 + (t >> 4)] = (tb + t >= TOUT) ? 1e30f : qs[c];
        }
    }
    __syncthreads();   // the ONE barrier

    // ---- 4) main loop: 8 tiles/wave; tile tau: i = (tau&15) + 512*(tau>>4),
    //         rows t = tb + i + 16*m (m 0..31), cols s = st*32 + n.
    float mcol[4] = {1e30f, 1e30f, 1e30f, 1e30f};
    const f32x16 zero16 = {0.f, 0.f, 0.f, 0.f, 0.f, 0.f, 0.f, 0.f,
                           0.f, 0.f, 0.f, 0.f, 0.f, 0.f, 0.f, 0.f};

    for (int rr = 0; rr < 8; ++rr) {
        const int tau = 8 * w + rr;
        const int i   = (tau & 15) + ((tau >> 4) << 9);
        const int p   = i & 7;
        // logical 16-B group of this lane's A-frag piece, channel 0
        const int gb  = p * 3 * XGRP + (i >> 3) + 2 * n + h;
        const s16x8 a0 = *(const s16x8*)((const char*)xph + (swz(gb)            << 4));
        const s16x8 a1 = *(const s16x8*)((const char*)xph + (swz(gb + XGRP)     << 4));
        const s16x8 a2 = *(const s16x8*)((const char*)xph + (swz(gb + 2 * XGRP) << 4));

        f32x16 acc[4];
        #pragma unroll
        for (int st = 0; st < 4; ++st) {
            acc[st] = __builtin_amdgcn_mfma_f32_32x32x16_bf16(a0, bfr[0][st], zero16, 0, 0, 0);
            acc[st] = __builtin_amdgcn_mfma_f32_32x32x16_bf16(a1, bfr[1][st], acc[st], 0, 0, 0);
            acc[st] = __builtin_amdgcn_mfma_f32_32x32x16_bf16(a2, bfr[2][st], acc[st], 0, 0, 0);
        }

        // winsq: 4 broadcast b128 reads (rows m64 = 8q + 4h + 32*ihi .. +3)
        const int ilow = i & 15, ihi = i >> 9;
        float4 wq[4];
        #pragma unroll
        for (int q = 0; q < 4; ++q)
            wq[q] = *(const float4*)&wsq[ilow * 64 + 8 * q + 4 * h + 32 * ihi];

        #pragma unroll
        for (int st = 0; st < 4; ++st)
            #pragma unroll
            for (int reg = 0; reg < 16; reg += 2) {
                const float u = acc[st][reg]     + ((const float*)&wq[reg >> 2])[0 + (reg & 3)];
                const float v = acc[st][reg + 1] + ((const float*)&wq[reg >> 2])[1 + (reg & 3)];
                mcol[st] = fminf(fminf(mcol[st], u), v);   // v_min3
            }
    }

    // ---- 5) reduce: +shsq once; lanes n / n+32 share column s = st*32+n
    #pragma unroll
    for (int st = 0; st < 4; ++st) {
        float mm = mcol[st] + shsqv[st];
        mm = fminf(mm, __shfl_xor(mm, 32, 64));
        if (h == 0) wavemin[w * Sn + st * 32 + n] = mm;
    }
    __syncthreads();
    if (tid < Sn) {
        const float mm = fminf(fminf(wavemin[tid], wavemin[Sn + tid]),
                               fminf(wavemin[2 * Sn + tid], wavemin[3 * Sn + tid]));
        partial[(b * NCH + chunk) * Sn + tid] = mm;
    }
}

// ------------------------------------------- final min over chunks + MLP head
__global__ __launch_bounds__(512) void mlp_kernel(const float* __restrict__ partial,
                                                  const float* __restrict__ W1,
                                                  const float* __restrict__ b1,
                                                  const float* __restrict__ W2,
                                                  const float* __restrict__ b2,
                                                  float* __restrict__ out) {
    __shared__ float pmin[4][Sn];
    __shared__ float db[Sn];
    __shared__ float hb[Hn];
    __shared__ float part[Cn][32];
    const int b = blockIdx.x, tid = threadIdx.x;

    // cooperative min over 16 chunks: 512 threads = 4 groups x 128 s
    {
        const int s = tid & 127, g = tid >> 7;
        const float* pp = partial + (b * NCH + g * 4) * Sn + s;
        float m = pp[0];
        #pragma unroll
        for (int c = 1; c < 4; ++c) m = fminf(m, pp[c * Sn]);
        pmin[g][s] = m;
    }
    __syncthreads();
    if (tid < Sn) {
        const float m = fminf(fminf(pmin[0][tid], pmin[1][tid]),
                              fminf(pmin[2][tid], pmin[3][tid]));
        db[tid] = m;
        out[b * Sn + tid] = m;             // distance output
    }
    __syncthreads();

    float a = b1[tid];
    const float4* w1r = (const float4*)(W1 + tid * Sn);
    const float4* dbv = (const float4*)db;
    #pragma unroll
    for (int i = 0; i < Sn / 4; ++i) {
        const float4 wv = w1r[i];
        const float4 dv = dbv[i];
        a = fmaf(dv.x, wv.x, a); a = fmaf(dv.y, wv.y, a);
        a = fmaf(dv.z, wv.z, a); a = fmaf(dv.w, wv.w, a);
    }
    hb[tid] = fmaxf(a, 0.0f);
    __syncthreads();

    if (tid < Cn * 32) {
        const int c = tid >> 5, p = tid & 31;
        float acc = 0.f;
        #pragma unroll
        for (int i = 0; i < Hn / 32; ++i)
            acc = fmaf(hb[p + 32 * i], W2[c * Hn + p + 32 * i], acc);
        part[c][p] = acc;
    }
    __syncthreads();
    if (tid < Cn) {
        float acc = b2[tid];
        #pragma unroll
        for (int p = 0; p < 32; ++p) acc += part[tid][p];
        out[Bn * Sn + b * Cn + tid] = acc; // classification output
    }
}

// ----------------------------------------------------------------- launcher
extern "C" void kernel_launch(void* const* d_in, const int* in_sizes, int n_in,
                              void* d_out, int out_size, void* d_ws, size_t ws_size,
                              hipStream_t stream) {
    const float* x  = (const float*)d_in[0];
    const float* sh = (const float*)d_in[1];
    const float* W1 = (const float*)d_in[2];
    const float* b1 = (const float*)d_in[3];
    const float* W2 = (const float*)d_in[4];
    const float* b2 = (const float*)d_in[5];
    float* out = (float*)d_out;
    float* partial = (float*)d_ws;   // 32*16*128 floats = 256 KB

    dist_kernel<<<Bn * NCH, 256, 0, stream>>>(x, sh, partial);
    mlp_kernel<<<Bn, 512, 0, stream>>>(partial, W1, b1, W2, b2, out);
}